// Round 1
// baseline (312.234 us; speedup 1.0000x reference)
//
#include <hip/hip_runtime.h>
#include <stdint.h>

typedef unsigned short u16;
typedef unsigned int u32;
typedef unsigned long long u64;
typedef __attribute__((ext_vector_type(4))) float f32x4;
typedef __attribute__((ext_vector_type(8))) short s16x8;
typedef __attribute__((ext_vector_type(4))) u16 u16x4;
typedef __attribute__((ext_vector_type(2))) u32 u32x2;
typedef __attribute__((ext_vector_type(4))) u32 u32x4;

#define NBATCH 4096
#define NS 50
#define NH 128
#define NNODE 50000
#define TW 1152      // table row width (Gin|Gout|Ghh)
#define KE 105       // extended K: 100 A-cols + rs_in hi/lo + rs_out hi/lo + ones
#define A2P 136      // A2 LDS pitch (elems)

// ---------- helpers ----------
__device__ __forceinline__ u16 f2bf(float f) {
  u32 u = __builtin_bit_cast(u32, f);
  u32 r = (u + 0x7FFFu + ((u >> 16) & 1u)) >> 16;
  return (u16)r;
}
__device__ __forceinline__ float bf2f(u16 u) {
  return __builtin_bit_cast(float, (u32)u << 16);
}
__device__ __forceinline__ float sigm(float x) {
  return 1.0f / (1.0f + __expf(-x));
}
__device__ __forceinline__ float tanh_(float x) {
  return 1.0f - 2.0f / (1.0f + __expf(2.0f * x));
}
__device__ __forceinline__ s16x8 pack8(f32x4 a, f32x4 b) {
  s16x8 r;
  r[0] = (short)f2bf(a[0]); r[1] = (short)f2bf(a[1]);
  r[2] = (short)f2bf(a[2]); r[3] = (short)f2bf(a[3]);
  r[4] = (short)f2bf(b[0]); r[5] = (short)f2bf(b[1]);
  r[6] = (short)f2bf(b[2]); r[7] = (short)f2bf(b[3]);
  return r;
}

// ---------- kernel 1: fold weights -> UcatT[1152][128] bf16, cvec[3][384] f32 ----------
__global__ __launch_bounds__(256) void k1_prep(
    const float* __restrict__ W_in, const float* __restrict__ b_in,
    const float* __restrict__ W_out, const float* __restrict__ b_out,
    const float* __restrict__ w_ih, const float* __restrict__ b_ih,
    const float* __restrict__ w_hh,
    const float* __restrict__ b_iah, const float* __restrict__ b_oah,
    u16* __restrict__ UcatT, float* __restrict__ cvec)
{
  int e = blockIdx.x * 256 + threadIdx.x;
  if (e < 147456) {
    int j = e >> 7, k = e & 127;
    float s = 0.f;
    if (j < 768) {
      // U_in[k][j]  = sum_h w_ih[j][h]     * W_in[h][k]
      // U_out[k][j'] = sum_h w_ih[j'][128+h] * W_out[h][k]
      const float* wr = w_ih + (size_t)(j < 384 ? j : j - 384) * 256 + (j < 384 ? 0 : 128);
      const float* Wc = (j < 384 ? W_in : W_out) + k;
      #pragma unroll 8
      for (int h = 0; h < 128; ++h) s += wr[h] * Wc[h * 128];
    } else {
      s = w_hh[(size_t)(j - 768) * 128 + k];
    }
    UcatT[e] = f2bf(s);
  } else if (e < 147456 + 1152) {
    int e2 = e - 147456;
    int which = e2 / 384, g = e2 - which * 384;
    const float* wr = w_ih + (size_t)g * 256;
    float s = 0.f;
    if (which == 0) { for (int h = 0; h < 128; ++h) s += wr[h] * b_in[h]; }
    else if (which == 1) { for (int h = 0; h < 128; ++h) s += wr[128 + h] * b_out[h]; }
    else {
      for (int h = 0; h < 128; ++h) s += wr[h] * b_iah[h] + wr[128 + h] * b_oah[h];
      s += b_ih[g];
    }
    cvec[which * 384 + g] = s;
  }
}

// ---------- kernel 2: node tables T[n][1152] = emb[n] @ UcatT^T (+b_hh on Ghh part) ----------
__global__ __launch_bounds__(256, 2) void k2_tables(
    const float* __restrict__ emb, const u16* __restrict__ UcatT,
    const float* __restrict__ b_hh, u16* __restrict__ T)
{
  int tid = threadIdx.x;
  int w = tid >> 6, l = tid & 63;
  int l16 = l & 15, g4 = l >> 4;
  int n0 = blockIdx.x * 64;

  // B-frags: emb rows (fp32 -> bf16), k = kt*32 + g4*8 + j
  s16x8 Bf[4][4];
  #pragma unroll
  for (int nt = 0; nt < 4; ++nt) {
    int nb = n0 + nt * 16 + l16; if (nb > NNODE - 1) nb = NNODE - 1;
    const float* ep = emb + (size_t)nb * NH + g4 * 8;
    #pragma unroll
    for (int kt = 0; kt < 4; ++kt) {
      f32x4 x = *(const f32x4*)(ep + kt * 32);
      f32x4 y = *(const f32x4*)(ep + kt * 32 + 4);
      Bf[nt][kt] = pack8(x, y);
    }
  }

  for (int mt = 0; mt < 18; ++mt) {
    int j0 = w * 288 + mt * 16;
    const u16* ap = UcatT + (size_t)(j0 + l16) * 128 + g4 * 8;
    s16x8 Af[4];
    #pragma unroll
    for (int kt = 0; kt < 4; ++kt) Af[kt] = *(const s16x8*)(ap + kt * 32);

    f32x4 acc[4] = {};
    #pragma unroll
    for (int nt = 0; nt < 4; ++nt)
      #pragma unroll
      for (int kt = 0; kt < 4; ++kt)
        acc[nt] = __builtin_amdgcn_mfma_f32_16x16x32_bf16(Af[kt], Bf[nt][kt], acc[nt], 0, 0, 0);

    int jr = j0 + g4 * 4;   // 4 consecutive j per lane (C rows)
    f32x4 bias = {0.f, 0.f, 0.f, 0.f};
    if (jr >= 768) bias = *(const f32x4*)(b_hh + (jr - 768));
    #pragma unroll
    for (int nt = 0; nt < 4; ++nt) {
      int ns = n0 + nt * 16 + l16;
      if (ns < NNODE) {
        u32 lo = (u32)f2bf(acc[nt][0] + bias[0]) | ((u32)f2bf(acc[nt][1] + bias[1]) << 16);
        u32 hi = (u32)f2bf(acc[nt][2] + bias[2]) | ((u32)f2bf(acc[nt][3] + bias[3]) << 16);
        u32x2 v = {lo, hi};
        *(u32x2*)(T + (size_t)ns * TW + jr) = v;
      }
    }
  }
}

// ---------- kernel 3: per-batch fused GEMM + GRU ----------
__global__ __launch_bounds__(256, 2) void k3_main(
    const int* __restrict__ inputs, const float* __restrict__ A,
    const u16* __restrict__ T, const float* __restrict__ cvec,
    const float* __restrict__ emb, float* __restrict__ out)
{
  __shared__ unsigned char GldsB[KE * 384];   // 105 rows x 384B (192 bf16 cols), XOR-swizzled
  __shared__ u16 A2lds[64 * A2P];             // [s][t] bf16, K-extended
  __shared__ u64 rowPtr[100];
  __shared__ int nodeIdx[64];

  int tid = threadIdx.x;
  int b = blockIdx.x;
  int w = tid >> 6, l = tid & 63;
  int l16 = l & 15, g4 = l >> 4;

  if (tid < 64) nodeIdx[tid] = inputs[b * NS + (tid < NS ? tid : 0)];
  if (tid < 100) {
    int node = inputs[b * NS + (tid < NS ? tid : tid - NS)];
    rowPtr[tid] = (u64)(uintptr_t)T + (u64)node * (TW * 2) + (u64)(tid < NS ? 0 : 768);
  }
  // zero A2 (covers pad rows/cols so MFMA sees no garbage)
  for (int e = tid; e < (64 * A2P * 2) / 16; e += 256) {
    u32x4 z = {0, 0, 0, 0};
    ((u32x4*)A2lds)[e] = z;
  }
  __syncthreads();

  // stage A[b] (50x100) -> bf16
  const float* Ab = A + (size_t)b * (NS * 2 * NS);
  for (int e = tid; e < 5000; e += 256) {
    int s = e / 100, c = e - s * 100;
    A2lds[s * A2P + c] = f2bf(Ab[e]);
  }
  __syncthreads();

  // rowsums (hi/lo split) + ones column
  if (tid < 100) {
    int s = tid < NS ? tid : tid - NS;
    int isOut = tid >= NS;
    float sum = 0.f;
    int off = isOut ? NS : 0;
    for (int t = 0; t < NS; ++t) sum += bf2f(A2lds[s * A2P + off + t]);
    u16 hi = f2bf(sum);
    A2lds[s * A2P + 100 + isOut * 2] = hi;
    A2lds[s * A2P + 101 + isOut * 2] = f2bf(sum - bf2f(hi));
  }
  if (tid < NS) A2lds[tid * A2P + 104] = 0x3F80;  // bf16(1.0)

  f32x4 accs[2][3][4] = {};

  #pragma unroll
  for (int hf = 0; hf < 2; ++hf) {
    __syncthreads();  // protects rs-writes (hf=0) / previous MFMA reads (hf=1)
    // gather G rows (t<100) for this g-half, XOR-swizzled b128 staging
    for (int q = tid; q < 2400; q += 256) {
      int t = q / 24, c = q - t * 24;
      u32x4 v = *(const u32x4*)(uintptr_t)(rowPtr[t] + (u64)(hf * 384 + c * 16));
      *(u32x4*)(GldsB + t * 384 + ((c * 16) ^ (((t >> 3) & 3) << 5))) = v;
    }
    // c-vector rows: 100,101=c_in ; 102,103=c_out ; 104=c0
    for (int e = tid; e < 5 * 192; e += 256) {
      int r = e / 192, col = e - r * 192;
      int which = (r < 2) ? 0 : ((r < 4) ? 1 : 2);
      float v = cvec[which * 384 + hf * 192 + col];
      int t = 100 + r;
      *(u16*)(GldsB + t * 384 + (((col * 2)) ^ (((t >> 3) & 3) << 5))) = f2bf(v);
    }
    __syncthreads();

    int cb[3];
    #pragma unroll
    for (int ml = 0; ml < 3; ++ml)
      cb[ml] = (((4 * ml + w) * 16 + l16) * 2) ^ (g4 << 5);

    #pragma unroll
    for (int kt = 0; kt < 4; ++kt) {
      s16x8 Bf[4];
      #pragma unroll
      for (int nt = 0; nt < 4; ++nt)
        Bf[nt] = *(const s16x8*)&A2lds[(nt * 16 + l16) * A2P + kt * 32 + g4 * 8];
      #pragma unroll
      for (int ml = 0; ml < 3; ++ml) {
        s16x8 Af;
        int tb = kt * 32 + g4 * 8;
        if (kt < 3) {
          #pragma unroll
          for (int j = 0; j < 8; ++j)
            Af[j] = (short)*(const u16*)(GldsB + (tb + j) * 384 + cb[ml]);
        } else {
          #pragma unroll
          for (int j = 0; j < 8; ++j) {
            int t = tb + j;
            u16 x = *(const u16*)(GldsB + (t < KE ? t : 0) * 384 + cb[ml]);
            Af[j] = (t < KE) ? (short)x : (short)0;
          }
        }
        #pragma unroll
        for (int nt = 0; nt < 4; ++nt)
          accs[hf][ml][nt] = __builtin_amdgcn_mfma_f32_16x16x32_bf16(Af, Bf[nt], accs[hf][ml][nt], 0, 0, 0);
      }
    }
  }

  // ---- in-register GRU epilogue ----
  // wave w holds complete (r,i,n) triples for h in [16w,16w+16) u [64+16w,64+16w+16)
  int pairs0 = 16 * w, pairs1 = 64 + 16 * w;
  #pragma unroll
  for (int nt = 0; nt < 4; ++nt) {
    int s = nt * 16 + l16;
    bool valid = s < NS;
    int node = nodeIdx[s];
    const u16* Trow = T + (size_t)node * TW;
    const float* erow = emb + (size_t)node * NH;
    float* orow = out + ((size_t)b * NS + s) * NH;
    #pragma unroll
    for (int p = 0; p < 2; ++p) {
      int hb = (p == 0 ? pairs0 : pairs1) + g4 * 4;
      u16x4 gr = *(const u16x4*)(Trow + 768 + hb);
      u16x4 gii = *(const u16x4*)(Trow + 768 + 128 + hb);
      u16x4 gnn = *(const u16x4*)(Trow + 768 + 256 + hb);
      f32x4 hid = *(const f32x4*)(erow + hb);
      f32x4 aR = (p == 0) ? accs[0][0][nt] : accs[0][1][nt];
      f32x4 aI = (p == 0) ? accs[0][2][nt] : accs[1][0][nt];
      f32x4 aN = (p == 0) ? accs[1][1][nt] : accs[1][2][nt];
      f32x4 res;
      #pragma unroll
      for (int rg = 0; rg < 4; ++rg) {
        float rr = sigm(aR[rg] + bf2f(gr[rg]));
        float ii = sigm(aI[rg] + bf2f(gii[rg]));
        float nn = tanh_(aN[rg] + rr * bf2f(gnn[rg]));
        res[rg] = nn + ii * (hid[rg] - nn);
      }
      if (valid) *(f32x4*)(orow + hb) = res;
    }
  }
}

// ---------- launcher ----------
extern "C" void kernel_launch(void* const* d_in, const int* in_sizes, int n_in,
                              void* d_out, int out_size, void* d_ws, size_t ws_size,
                              hipStream_t stream) {
  const int*   inputs = (const int*)  d_in[0];
  const float* A      = (const float*)d_in[1];
  const float* emb    = (const float*)d_in[2];
  const float* W_in   = (const float*)d_in[3];
  const float* b_in   = (const float*)d_in[4];
  const float* W_out  = (const float*)d_in[5];
  const float* b_out  = (const float*)d_in[6];
  const float* w_ih   = (const float*)d_in[7];
  const float* b_ih   = (const float*)d_in[8];
  const float* w_hh   = (const float*)d_in[9];
  const float* b_hh   = (const float*)d_in[10];
  const float* b_iah  = (const float*)d_in[11];
  const float* b_oah  = (const float*)d_in[12];

  // ws layout: T (50000*1152 bf16 = 115,200,000 B) | UcatT (294,912 B) | cvec (4,608 B)
  u16*   T     = (u16*)d_ws;
  u16*   UcatT = (u16*)((char*)d_ws + 115200000);
  float* cvec  = (float*)((char*)d_ws + 115200000 + 294912);

  k1_prep<<<dim3(581), dim3(256), 0, stream>>>(W_in, b_in, W_out, b_out, w_ih, b_ih,
                                               w_hh, b_iah, b_oah, UcatT, cvec);
  k2_tables<<<dim3(782), dim3(256), 0, stream>>>(emb, UcatT, b_hh, T);
  k3_main<<<dim3(4096), dim3(256), 0, stream>>>(inputs, A, T, cvec, emb, (float*)d_out);
}